// Round 10
// baseline (341.115 us; speedup 1.0000x reference)
//
#include <hip/hip_runtime.h>
#include <hip/hip_cooperative_groups.h>
#include <math.h>

namespace cg = cooperative_groups;

#define BSZ 512
#define DD 2048
#define KK 128
#define PP 5
#define NCOL 640        // KK*PP
#define OUTW 2176       // DD+KK
#define LOG2E 1.4426950408889634f

#define GM 64           // gemm m rows per tile (lane dim)
#define GN 40           // gemm n cols per tile (4 waves x 10)
#define KSPLIT 16
#define GK 128          // DD/KSPLIT
#define GBK 32          // k chunk staged in LDS
#define QS 16           // pairwise b2 chunks of 32 rows
#define GRID 512        // coop grid: 2 blocks/CU needed (supported to 4) — margin

// shared ws layout (floats), used by BOTH paths:
#define WS_SCALE 0
#define WS_ACTV 640
#define WS_FPART (WS_ACTV + BSZ * NCOL)        // f_part[16*128*512]
#define WS_PART  (WS_FPART + QS * KK * BSZ)    // part[16*512*640]

// ===========================================================================
// PATH 1: single cooperative kernel, 512 blocks x 256 threads.
// Phases split by grid.sync(); 8 KiB LDS reused. No atomics anywhere.
// ===========================================================================
__global__ __launch_bounds__(256, 4) void mega_kernel(
        const float* __restrict__ x, const float* __restrict__ theta,
        const float* __restrict__ lws, const float* __restrict__ bias,
        float* __restrict__ out, float* __restrict__ ws) {
    cg::grid_group grid = cg::this_grid();

    float* scale  = ws + WS_SCALE;
    float* actv   = ws + WS_ACTV;
    float* f_part = ws + WS_FPART;
    float* part   = ws + WS_PART;

    __shared__ float lds[GBK * GM];   // 8 KiB, reused across phases

    const int bid  = blockIdx.x;
    const int tid  = threadIdx.x;
    const int lane = tid & 63;
    const int wave = tid >> 6;

    // ---- A1: copy x -> out[:, :D]  (grid-stride, 2 iters of float4) ----
    for (int i = bid * 256 + tid; i < BSZ * 512; i += GRID * 256) {
        int r = i >> 9;
        int c = i & 511;
        float4 v = *(const float4*)&x[(size_t)r * DD + c * 4];
        *(float4*)&out[(size_t)r * OUTW + c * 4] = v;
    }

    // ---- A2: blocks [0,40): norm of 16 cols -> scale[col] ----
    if (bid < 40) {
        float (*snorm)[17] = (float(*)[17])lds;
        const int col0 = bid * 16;
        const int co  = tid & 15;
        const int seg = tid >> 4;
        const float* p = theta + (size_t)seg * 128 * NCOL + col0 + co;
        float s = 0.f;
        for (int j = 0; j < 128; ++j) {
            float v = p[(size_t)j * NCOL];
            s += v * v;
        }
        snorm[seg][co] = s;
        __syncthreads();
        if (tid < 16) {
            float t = 0.f;
#pragma unroll
            for (int g = 0; g < 16; ++g) t += snorm[g][tid];
            const int col = col0 + tid;
            scale[col] = __builtin_amdgcn_exp2f(lws[col] * LOG2E) *
                         __builtin_amdgcn_rsqf(t) * LOG2E;
        }
        __syncthreads();   // snorm reads done before gemm reuses lds
    }

    // ---- A3: gemm, 4 tiles per block (512*4 = 2048 tiles exact) ----
    {
        float (*xT)[GM] = (float(*)[GM])lds;
#pragma unroll 1
        for (int rep = 0; rep < 4; ++rep) {
            const int tile = bid * 4 + rep;            // 0..2047
            const int z   = tile >> 7;                 // 0..15
            const int rem = tile & 127;
            const int mt  = rem >> 4;                  // 0..7
            const int nt  = rem & 15;                  // 0..15
            const int m   = mt * GM + lane;
            const int kz  = z * GK;
            const int nw  = __builtin_amdgcn_readfirstlane(nt * GN + wave * 10);

            const float* xrow = x + (size_t)m * DD;
            float acc[10] = {};

            float4 v0 = *(const float4*)&xrow[kz + wave * 8];
            float4 v1 = *(const float4*)&xrow[kz + wave * 8 + 4];

            for (int kc = kz; kc < kz + GK; kc += GBK) {
                __syncthreads();   // previous LDS readers done
                xT[wave * 8 + 0][lane] = v0.x;
                xT[wave * 8 + 1][lane] = v0.y;
                xT[wave * 8 + 2][lane] = v0.z;
                xT[wave * 8 + 3][lane] = v0.w;
                xT[wave * 8 + 4][lane] = v1.x;
                xT[wave * 8 + 5][lane] = v1.y;
                xT[wave * 8 + 6][lane] = v1.z;
                xT[wave * 8 + 7][lane] = v1.w;
                __syncthreads();

                if (kc + GBK < kz + GK) {   // next chunk's loads in flight
                    v0 = *(const float4*)&xrow[kc + GBK + wave * 8];
                    v1 = *(const float4*)&xrow[kc + GBK + wave * 8 + 4];
                }

                const float* th = &theta[(size_t)kc * NCOL + nw];
#pragma unroll 4
                for (int kk = 0; kk < GBK; ++kk) {
                    const float a = xT[kk][lane];
#pragma unroll
                    for (int j = 0; j < 10; ++j)
                        acc[j] += a * th[(size_t)kk * NCOL + j];  // wave-uniform
                }
            }

            float* dst = part + (size_t)z * (BSZ * NCOL) + (size_t)m * NCOL + nw;
#pragma unroll
            for (int j = 0; j < 5; ++j)
                *(float2*)&dst[2 * j] = make_float2(acc[2 * j], acc[2 * j + 1]);
        }
    }

    grid.sync();

    // ---- B: reduce split-K partials * scale -> actv (grid-stride) ----
    for (int i = bid * 256 + tid; i < BSZ * NCOL; i += GRID * 256) {
        int col = i % NCOL;
        float s = 0.f;
#pragma unroll
        for (int q = 0; q < KSPLIT; ++q)
            s += part[(size_t)q * (BSZ * NCOL) + i];
        actv[i] = s * scale[col];
    }

    grid.sync();

    // ---- C: pairwise; 2 units per 128-thread half (2048 units total) ----
    {
        const int h    = tid >> 7;          // 0..1
        const int t128 = tid & 127;
        float (*sB)[8] = ((float(*)[8])lds) + h * 32;   // 32 rows x 8 per half

#pragma unroll 1
        for (int uu = 0; uu < 2; ++uu) {
            const int unit = bid * 2 + h + uu * 1024;   // 0..2047
            const int k = unit >> 4;        // 0..127
            const int q = unit & 15;        // 0..15

            __syncthreads();                // prior sB readers done
            for (int i = t128; i < 32 * PP; i += 128) {   // 160 entries
                int r = i / PP;
                int p = i - r * PP;
                sB[r][p] = actv[(size_t)(q * 32 + r) * NCOL + k * PP + p];
            }

            float a[4][PP];
#pragma unroll
            for (int r = 0; r < 4; ++r) {
                const float* ap = &actv[(size_t)(t128 + r * 128) * NCOL + k * PP];
#pragma unroll
                for (int p = 0; p < PP; ++p) a[r][p] = ap[p];
            }
            __syncthreads();

            float acc[4] = {0.f, 0.f, 0.f, 0.f};
#pragma unroll 2
            for (int j = 0; j < 32; ++j) {
                const float4 v  = *(const float4*)&sB[j][0];
                const float  v4 = sB[j][4];
#pragma unroll
                for (int r = 0; r < 4; ++r) {
                    float s = fabsf(a[r][0] - v.x) + fabsf(a[r][1] - v.y) +
                              fabsf(a[r][2] - v.z) + fabsf(a[r][3] - v.w) +
                              fabsf(a[r][4] - v4);
                    acc[r] += __builtin_amdgcn_exp2f(-s);  // pre-scaled by log2e
                }
            }

            float* fp = f_part + ((size_t)q * KK + k) * BSZ;
#pragma unroll
            for (int r = 0; r < 4; ++r)
                fp[t128 + r * 128] = acc[r];    // plain coalesced stores
        }
    }

    grid.sync();

    // ---- D: finalize -> out[:, D:] ----
    if (bid < 256) {
        int i = bid * 256 + tid;            // 0..65535
        int k = i >> 9;
        int b = i & 511;
        float s = 0.f;
#pragma unroll
        for (int q = 0; q < QS; ++q)
            s += f_part[((size_t)q * KK + k) * BSZ + b];
        out[(size_t)b * OUTW + DD + k] = s - 1.0f + bias[k];
    }
}

// ===========================================================================
// PATH 2 (fallback, R7-proven): 5 separate kernels, same ws layout.
// ===========================================================================
__global__ __launch_bounds__(256) void prep_kernel(const float* __restrict__ x,
                                                   const float* __restrict__ theta,
                                                   const float* __restrict__ lws,
                                                   float* __restrict__ out,
                                                   float* __restrict__ scale) {
    const int bid = blockIdx.x;
    const int tid = threadIdx.x;
    if (bid < 1024) {
        int i = bid * 256 + tid;
        int r = i >> 9;
        int c = i & 511;
        float4 v = *(const float4*)&x[(size_t)r * DD + c * 4];
        *(float4*)&out[(size_t)r * OUTW + c * 4] = v;
    } else {
        __shared__ float snorm[16][17];
        const int col0 = (bid - 1024) * 16;
        const int co  = tid & 15;
        const int seg = tid >> 4;
        const float* p = theta + (size_t)seg * 128 * NCOL + col0 + co;
        float s = 0.f;
        for (int j = 0; j < 128; ++j) {
            float v = p[(size_t)j * NCOL];
            s += v * v;
        }
        snorm[seg][co] = s;
        __syncthreads();
        if (tid < 16) {
            float t = 0.f;
#pragma unroll
            for (int g = 0; g < 16; ++g) t += snorm[g][tid];
            const int col = col0 + tid;
            scale[col] = __builtin_amdgcn_exp2f(lws[col] * LOG2E) *
                         __builtin_amdgcn_rsqf(t) * LOG2E;
        }
    }
}

__global__ __launch_bounds__(256) void gemm_kernel(const float* __restrict__ x,
                                                   const float* __restrict__ theta,
                                                   float* __restrict__ part) {
    __shared__ float xT[GBK][GM];
    const int t    = threadIdx.x;
    const int lane = t & 63;
    const int wave = t >> 6;
    const int m    = blockIdx.y * GM + lane;
    const int kz   = blockIdx.z * GK;
    const int nw = __builtin_amdgcn_readfirstlane(blockIdx.x * 32 + wave * 8);

    const float* xrow = x + (size_t)m * DD;
    float acc[8] = {};
    float4 v0 = *(const float4*)&xrow[kz + wave * 8];
    float4 v1 = *(const float4*)&xrow[kz + wave * 8 + 4];

    for (int kc = kz; kc < kz + GK; kc += GBK) {
        __syncthreads();
        xT[wave * 8 + 0][lane] = v0.x;
        xT[wave * 8 + 1][lane] = v0.y;
        xT[wave * 8 + 2][lane] = v0.z;
        xT[wave * 8 + 3][lane] = v0.w;
        xT[wave * 8 + 4][lane] = v1.x;
        xT[wave * 8 + 5][lane] = v1.y;
        xT[wave * 8 + 6][lane] = v1.z;
        xT[wave * 8 + 7][lane] = v1.w;
        __syncthreads();
        if (kc + GBK < kz + GK) {
            v0 = *(const float4*)&xrow[kc + GBK + wave * 8];
            v1 = *(const float4*)&xrow[kc + GBK + wave * 8 + 4];
        }
        const float* th = &theta[(size_t)kc * NCOL + nw];
#pragma unroll 4
        for (int kk = 0; kk < GBK; ++kk) {
            const float a = xT[kk][lane];
#pragma unroll
            for (int j = 0; j < 8; ++j)
                acc[j] += a * th[(size_t)kk * NCOL + j];
        }
    }
    float* dst = part + (size_t)blockIdx.z * (BSZ * NCOL) + (size_t)m * NCOL + nw;
    *(float4*)&dst[0] = make_float4(acc[0], acc[1], acc[2], acc[3]);
    *(float4*)&dst[4] = make_float4(acc[4], acc[5], acc[6], acc[7]);
}

__global__ __launch_bounds__(256) void reduce_kernel(const float* __restrict__ part,
                                                     const float* __restrict__ scale,
                                                     float* __restrict__ actv) {
    int i   = blockIdx.x * 256 + threadIdx.x;
    int col = i % NCOL;
    float s = 0.f;
#pragma unroll
    for (int q = 0; q < KSPLIT; ++q)
        s += part[(size_t)q * (BSZ * NCOL) + i];
    actv[i] = s * scale[col];
}

__global__ __launch_bounds__(128) void pairwise_kernel(const float* __restrict__ actv,
                                                       float* __restrict__ f_part) {
    const int k   = blockIdx.x;
    const int q   = blockIdx.y;     // 0..15, 32-row chunks
    const int tid = threadIdx.x;
    __shared__ float sB[32][8];

    for (int i = tid; i < 32 * PP; i += 128) {
        int r = i / PP;
        int p = i - r * PP;
        sB[r][p] = actv[(size_t)(q * 32 + r) * NCOL + k * PP + p];
    }
    float a[4][PP];
#pragma unroll
    for (int r = 0; r < 4; ++r) {
        const float* ap = &actv[(size_t)(tid + r * 128) * NCOL + k * PP];
#pragma unroll
        for (int p = 0; p < PP; ++p) a[r][p] = ap[p];
    }
    __syncthreads();

    float acc[4] = {0.f, 0.f, 0.f, 0.f};
#pragma unroll 2
    for (int j = 0; j < 32; ++j) {
        const float4 v  = *(const float4*)&sB[j][0];
        const float  v4 = sB[j][4];
#pragma unroll
        for (int r = 0; r < 4; ++r) {
            float s = fabsf(a[r][0] - v.x) + fabsf(a[r][1] - v.y) +
                      fabsf(a[r][2] - v.z) + fabsf(a[r][3] - v.w) +
                      fabsf(a[r][4] - v4);
            acc[r] += __builtin_amdgcn_exp2f(-s);
        }
    }
    float* fp = f_part + ((size_t)q * KK + k) * BSZ;
#pragma unroll
    for (int r = 0; r < 4; ++r)
        fp[tid + r * 128] = acc[r];
}

__global__ __launch_bounds__(256) void finalize_kernel(const float* __restrict__ f_part,
                                                       const float* __restrict__ bias,
                                                       float* __restrict__ out) {
    int i = blockIdx.x * 256 + threadIdx.x;
    int k = i >> 9;
    int b = i & 511;
    float s = 0.f;
#pragma unroll
    for (int q = 0; q < QS; ++q)
        s += f_part[((size_t)q * KK + k) * BSZ + b];
    out[(size_t)b * OUTW + DD + k] = s - 1.0f + bias[k];
}

// ---------------------------------------------------------------------------
extern "C" void kernel_launch(void* const* d_in, const int* in_sizes, int n_in,
                              void* d_out, int out_size, void* d_ws, size_t ws_size,
                              hipStream_t stream) {
    const float* x     = (const float*)d_in[0];   // [512, 2048]
    const float* theta = (const float*)d_in[1];   // [2048, 128, 5]
    const float* lws   = (const float*)d_in[2];   // [128, 5]
    const float* bias  = (const float*)d_in[3];   // [128]
    float* out = (float*)d_out;                   // [512, 2176]
    float* ws  = (float*)d_ws;

    void* args[] = {(void*)&x, (void*)&theta, (void*)&lws, (void*)&bias,
                    (void*)&out, (void*)&ws};
    hipError_t err = hipLaunchCooperativeKernel((const void*)mega_kernel,
                                                dim3(GRID), dim3(256),
                                                args, 0, stream);
    if (err != hipSuccess) {
        // deterministic fallback: proven 5-kernel path, same ws layout
        float* scale  = ws + WS_SCALE;
        float* actv   = ws + WS_ACTV;
        float* f_part = ws + WS_FPART;
        float* part   = ws + WS_PART;
        prep_kernel<<<1064, 256, 0, stream>>>(x, theta, lws, out, scale);
        gemm_kernel<<<dim3(NCOL / 32, BSZ / GM, KSPLIT), 256, 0, stream>>>(x, theta, part);
        reduce_kernel<<<(BSZ * NCOL) / 256, 256, 0, stream>>>(part, scale, actv);
        pairwise_kernel<<<dim3(KK, QS), 128, 0, stream>>>(actv, f_part);
        finalize_kernel<<<(BSZ * KK) / 256, 256, 0, stream>>>(f_part, bias, out);
    }
}